// Round 11
// baseline (305.495 us; speedup 1.0000x reference)
//
#include <hip/hip_runtime.h>
#include <hip/hip_bf16.h>

#define NN 8192
#define DD 128
#define DQK 256
#define EE 262144
#define EDGE_DIM 50
#define HID 32
#define CAP 96                               // per-row edge cap (Poisson(32))
#define SCALE 0.08838834764831845f          // 1/sqrt(128)
#define SCALE_LOG2E 0.12752455522410585f    // SCALE * log2(e)

using f32x4 = __attribute__((ext_vector_type(4))) float;
using f32x2 = __attribute__((ext_vector_type(2))) float;
using bf16x8 = __attribute__((ext_vector_type(8))) short;  // 8 bf16 = 4 VGPRs
using s16x4 = __attribute__((ext_vector_type(4))) short;

static __device__ __forceinline__ short f2b(float f) {
  __hip_bfloat16 h = __float2bfloat16(f);
  return __builtin_bit_cast(short, h);
}
static __device__ __forceinline__ float b2f(short s) {
  unsigned u = ((unsigned)(unsigned short)s) << 16;
  return __builtin_bit_cast(float, u);
}
// async global->LDS, 16B per lane; lds dest = wave-uniform base + lane*16
static __device__ __forceinline__ void gll(const short* g, short* l) {
  __builtin_amdgcn_global_load_lds(
      (const __attribute__((address_space(1))) void*)g,
      (__attribute__((address_space(3))) void*)l, 16, 0, 0);
}

// ---------------- K1: heterogeneous prep + MLP, one dispatch -----------------
// blocks [0,4096):    qkb[n][0:128]=mag*cos, [128:256]=mag*sin (elementwise)
// blocks [4096,4608): vtb[f][n] transpose via 64x64 LDS tiles
// blocks [4608,5120): edge MLP, 2 edges/thread (halves uniform W1 LDS reads)
__global__ __launch_bounds__(256) void k1_mega(
    const float* __restrict__ mag, const float* __restrict__ phase,
    short* __restrict__ qkb, short* __restrict__ vtb,
    const float* __restrict__ rbf, const float* __restrict__ W1,
    const float* __restrict__ b1, const float* __restrict__ W2,
    const float* __restrict__ b2, const int* __restrict__ eidx,
    float* __restrict__ bias, int* __restrict__ cnt, int* __restrict__ slot) {
  __shared__ float tile[64][65];
  __shared__ alignas(16) float w1s[EDGE_DIM * HID];
  __shared__ alignas(16) float b1s[HID];
  __shared__ alignas(16) float w2s[HID];
  __shared__ float b2s;
  int b = blockIdx.x;
  int tid = threadIdx.x;
  if (b < 4096) {
    int t = b * 256 + tid;
    int n = t >> 7, d = t & 127;
    float m = mag[t], p = phase[t];
    float sn, cs;
    __sincosf(p, &sn, &cs);
    qkb[(size_t)n * DQK + d] = f2b(m * cs);
    qkb[(size_t)n * DQK + 128 + d] = f2b(m * sn);
    return;
  }
  if (b < 4608) {
    int r = b - 4096;
    int bn = r & 127, bd = (r >> 7) & 1, sel = r >> 8;
    const float* src = sel ? phase : mag;
#pragma unroll
    for (int rep = 0; rep < 16; ++rep) {
      int idx = rep * 256 + tid;
      int rr = idx >> 6, c = idx & 63;
      tile[rr][c] = src[(size_t)(bn * 64 + rr) * DD + bd * 64 + c];
    }
    __syncthreads();
#pragma unroll
    for (int rep = 0; rep < 16; ++rep) {
      int idx = rep * 256 + tid;
      int rr = idx >> 6, c = idx & 63;
      vtb[(size_t)(sel * 128 + bd * 64 + rr) * NN + bn * 64 + c] = f2b(tile[c][rr]);
    }
    return;
  }
  // ---- MLP branch: 2 edges per thread ----
  for (int k = tid; k < EDGE_DIM * HID; k += 256) w1s[k] = W1[k];
  if (tid < HID) { b1s[tid] = b1[tid]; w2s[tid] = W2[tid]; }
  if (tid == 0) b2s = b2[0];
  __syncthreads();
  int e0 = (b - 4608) * 512 + tid;
  int e1 = e0 + 256;
  const float* ra = rbf + (size_t)e0 * EDGE_DIM;
  const float* rbp = rbf + (size_t)e1 * EDGE_DIM;
  f32x4 r4a[12], r4b[12];
#pragma unroll
  for (int k = 0; k < 12; ++k) {
    r4a[k] = *reinterpret_cast<const f32x4*>(ra + 4 * k);
    r4b[k] = *reinterpret_cast<const f32x4*>(rbp + 4 * k);
  }
  f32x2 ta = *reinterpret_cast<const f32x2*>(ra + 48);
  f32x2 tb = *reinterpret_cast<const f32x2*>(rbp + 48);
  f32x4 ha[8], hb[8];
#pragma unroll
  for (int jj = 0; jj < 8; ++jj) {
    f32x4 bv = reinterpret_cast<const f32x4*>(b1s)[jj];
    ha[jj] = bv;
    hb[jj] = bv;
  }
#pragma unroll
  for (int k = 0; k < 12; ++k) {
#pragma unroll
    for (int qq = 0; qq < 4; ++qq) {
      const f32x4* wrow = reinterpret_cast<const f32x4*>(w1s + (4 * k + qq) * HID);
      float sa = r4a[k][qq], sb = r4b[k][qq];
#pragma unroll
      for (int jj = 0; jj < 8; ++jj) {
        f32x4 wv = wrow[jj];
        ha[jj] += sa * wv;
        hb[jj] += sb * wv;
      }
    }
  }
  {
    const f32x4* w48 = reinterpret_cast<const f32x4*>(w1s + 48 * HID);
    const f32x4* w49 = reinterpret_cast<const f32x4*>(w1s + 49 * HID);
#pragma unroll
    for (int jj = 0; jj < 8; ++jj) {
      f32x4 wv0 = w48[jj], wv1 = w49[jj];
      ha[jj] += ta.x * wv0 + ta.y * wv1;
      hb[jj] += tb.x * wv0 + tb.y * wv1;
    }
  }
  float outa = b2s, outb = b2s;
#pragma unroll
  for (int jj = 0; jj < 8; ++jj) {
    f32x4 wv = reinterpret_cast<const f32x4*>(w2s)[jj];
    f32x4 xa = ha[jj], xb = hb[jj];
#pragma unroll
    for (int q = 0; q < 4; ++q) {
      outa += wv[q] * (xa[q] / (1.0f + __expf(-xa[q])));
      outb += wv[q] * (xb[q] / (1.0f + __expf(-xb[q])));
    }
  }
  bias[e0] = outa;
  bias[e1] = outb;
  int i0 = eidx[e0];
  int p0 = atomicAdd(&cnt[i0], 1);
  if (p0 < CAP) slot[i0 * CAP + p0] = e0;
  int i1 = eidx[e1];
  int p1 = atomicAdd(&cnt[i1], 1);
  if (p1 < CAP) slot[i1 * CAP + p1] = e1;
}

// ---------------- K5: fused dense flash (R8-proven structure) ----------------
// TBM=64 rows/block, 512 threads = 8 waves (2 row x 4 col). LDS exactly 80 KiB
// (Qs 32K + KV 32K + Ps 16K, dl overlaid on KV) -> 2 blocks/CU. Fine-grained
// K-slice double-buffering (4 x 16KB) is LOAD-BEARING for L2 reuse: fat-phase
// burst staging (R9) collapsed L2 hit rate (FETCH 14->278 MB). Do not coarsen.
// R11: V-jb0 DMA issued before the exp phase (KV free after last bk barrier),
// one barrier covers Ps + V0 visibility -> 9 barriers/chunk (was 10).
constexpr int TBM = 64;
constexpr int TBN = 128;

template <int NSPLIT>
__global__ __launch_bounds__(512, 4) void k5_flash(
    const short* __restrict__ qk,  // [N][256] bf16
    const short* __restrict__ vt,  // [256][N] bf16
    float* __restrict__ nump,      // [NSPLIT][N][256]
    float* __restrict__ denp) {    // [NSPLIT][N]
  constexpr int QCOLS = NN / NSPLIT;
  constexpr int NCHUNK = QCOLS / TBN;
  constexpr int GPQ = 8 / NSPLIT;
  __shared__ alignas(16) short Qs[TBM * 256];     // 32 KiB, swizzled
  __shared__ alignas(16) short KV[2 * TBN * 64];  // 32 KiB: K dbuf / V subtile
  __shared__ alignas(16) short Ps[TBM * 128];     // 16 KiB, swizzled
  int b = blockIdx.x;
  int q = (b & 7) / GPQ;
  int rb = (b >> 3) * GPQ + (b & (GPQ - 1));
  int tid = threadIdx.x;
  int w = tid >> 6, lane = tid & 63;
  int wr = w >> 2, wc = w & 3;
  int l15 = lane & 15, quad = lane >> 4;
  int rsw = l15 & 7;  // read-side swizzle key (row&7 == l15&7 for all frags)
  int wbase = w * 64; // lane-linear staging base per wave
  int r0 = rb * TBM;
  int cbase = q * QCOLS;

  // ---- stage Q tile once: 4 passes x 8KB, direct to LDS ----
#pragma unroll
  for (int p = 0; p < 4; ++p) {
    int idx = p * 512 + tid;
    int row = idx >> 5, gs = idx & 31;
    gll(qk + (size_t)(r0 + row) * DQK + ((gs ^ (row & 7)) * 8),
        &Qs[(p * 512 + wbase) * 8]);
  }

  f32x4 o[2][4] = {};
  float den[2][4] = {};
  __syncthreads();

  for (int ch = 0; ch < NCHUNK; ++ch) {
    int c0 = cbase + ch * TBN;
    // ---- stage K slice bk=0 into buf0 ----
#pragma unroll
    for (int p = 0; p < 2; ++p) {
      int idx = p * 512 + tid;
      int col = idx >> 3, gs = idx & 7;
      gll(qk + (size_t)(c0 + col) * DQK + ((gs ^ (col & 7)) * 8),
          &KV[(p * 512 + wbase) * 8]);
    }
    __syncthreads();
    f32x4 s[2][2] = {};
#pragma unroll
    for (int bk = 0; bk < 4; ++bk) {
      int buf = bk & 1;
      if (bk < 3) {
        int nb = buf ^ 1;
#pragma unroll
        for (int p = 0; p < 2; ++p) {
          int idx = p * 512 + tid;
          int col = idx >> 3, gs = idx & 7;
          gll(qk + (size_t)(c0 + col) * DQK + (bk + 1) * 64 + ((gs ^ (col & 7)) * 8),
              &KV[nb * 8192 + (p * 512 + wbase) * 8]);
        }
      }
#pragma unroll
      for (int ks = 0; ks < 2; ++ks) {
        int g = ks * 4 + quad;
        bf16x8 a[2], bb[2];
#pragma unroll
        for (int rt = 0; rt < 2; ++rt)
          a[rt] = *(const bf16x8*)&Qs[(wr * 32 + rt * 16 + l15) * 256 +
                                      ((bk * 8 + g) ^ rsw) * 8];
#pragma unroll
        for (int ct = 0; ct < 2; ++ct)
          bb[ct] = *(const bf16x8*)&KV[buf * 8192 + (wc * 32 + ct * 16 + l15) * 64 +
                                       (g ^ rsw) * 8];
#pragma unroll
        for (int rt = 0; rt < 2; ++rt)
#pragma unroll
          for (int ct = 0; ct < 2; ++ct)
            s[rt][ct] = __builtin_amdgcn_mfma_f32_16x16x32_bf16(a[rt], bb[ct],
                                                                s[rt][ct], 0, 0, 0);
      }
      __syncthreads();  // after bk=3: all K reads done -> KV free
    }
    // ---- stage V jb=0 subtile now (DMA overlaps the exp phase below) ----
#pragma unroll
    for (int p = 0; p < 4; ++p) {
      int idx = p * 512 + tid;
      int feat = idx >> 3, gs = idx & 7;
      gll(vt + (size_t)feat * NN + c0 + ((gs ^ (feat & 7)) * 8),
          &KV[(p * 512 + wbase) * 8]);
    }
    // ---- exp + P->LDS (C layout, swizzled groups) + den ----
#pragma unroll
    for (int rt = 0; rt < 2; ++rt)
#pragma unroll
      for (int ct = 0; ct < 2; ++ct) {
        int col = wc * 32 + ct * 16 + l15;
        int cg = col >> 3, co = col & 7;
#pragma unroll
        for (int r = 0; r < 4; ++r) {
          float pv = exp2f(s[rt][ct][r] * SCALE_LOG2E);
          den[rt][r] += pv;
          int row = wr * 32 + rt * 16 + quad * 4 + r;
          Ps[row * 128 + ((cg ^ (row & 7)) * 8 + co)] = f2b(pv);
        }
      }
    __syncthreads();  // Ps visible AND V jb0 arrived (barrier drains vmcnt)
    // ---- PV jb=0 ----
#pragma unroll
    for (int ks = 0; ks < 2; ++ks) {
      int g = ks * 4 + quad;
      bf16x8 pa[2], vb[4];
#pragma unroll
      for (int rt = 0; rt < 2; ++rt) {
        int row = wr * 32 + rt * 16 + l15;
        pa[rt] = *(const bf16x8*)&Ps[row * 128 + ((g ^ (row & 7)) * 8)];
      }
#pragma unroll
      for (int ft = 0; ft < 4; ++ft)
        vb[ft] = *(const bf16x8*)&KV[(wc * 64 + ft * 16 + l15) * 64 + (g ^ rsw) * 8];
#pragma unroll
      for (int rt = 0; rt < 2; ++rt)
#pragma unroll
        for (int ft = 0; ft < 4; ++ft)
          o[rt][ft] = __builtin_amdgcn_mfma_f32_16x16x32_bf16(pa[rt], vb[ft],
                                                              o[rt][ft], 0, 0, 0);
    }
    __syncthreads();  // V jb0 reads done
    // ---- stage V jb=1 subtile ----
#pragma unroll
    for (int p = 0; p < 4; ++p) {
      int idx = p * 512 + tid;
      int feat = idx >> 3, gs = idx & 7;
      gll(vt + (size_t)feat * NN + c0 + 64 + ((gs ^ (feat & 7)) * 8),
          &KV[(p * 512 + wbase) * 8]);
    }
    __syncthreads();  // V jb1 visible
    // ---- PV jb=1 ----
#pragma unroll
    for (int ks = 0; ks < 2; ++ks) {
      int g = ks * 4 + quad;
      bf16x8 pa[2], vb[4];
#pragma unroll
      for (int rt = 0; rt < 2; ++rt) {
        int row = wr * 32 + rt * 16 + l15;
        pa[rt] = *(const bf16x8*)&Ps[row * 128 + (((8 + g) ^ (row & 7)) * 8)];
      }
#pragma unroll
      for (int ft = 0; ft < 4; ++ft)
        vb[ft] = *(const bf16x8*)&KV[(wc * 64 + ft * 16 + l15) * 64 + (g ^ rsw) * 8];
#pragma unroll
      for (int rt = 0; rt < 2; ++rt)
#pragma unroll
        for (int ft = 0; ft < 4; ++ft)
          o[rt][ft] = __builtin_amdgcn_mfma_f32_16x16x32_bf16(pa[rt], vb[ft],
                                                              o[rt][ft], 0, 0, 0);
    }
    __syncthreads();  // V jb1 reads done (protects next chunk's K stage)
  }
  // ---- epilogue: write partial num ----
  float* npB = nump + (size_t)q * NN * DQK;
#pragma unroll
  for (int rt = 0; rt < 2; ++rt)
#pragma unroll
    for (int ft = 0; ft < 4; ++ft) {
      int row = r0 + wr * 32 + rt * 16 + quad * 4;
      int feat = wc * 64 + ft * 16 + l15;
#pragma unroll
      for (int r = 0; r < 4; ++r)
        npB[(size_t)(row + r) * DQK + feat] = o[rt][ft][r];
    }
  // ---- den: reduce l15 within quad, then across col-waves (dl overlays KV) --
  float* dl = reinterpret_cast<float*>(KV);  // [4][TBM], KV dead at epilogue
#pragma unroll
  for (int rt = 0; rt < 2; ++rt)
#pragma unroll
    for (int r = 0; r < 4; ++r) {
      float d = den[rt][r];
      d += __shfl_xor(d, 1);
      d += __shfl_xor(d, 2);
      d += __shfl_xor(d, 4);
      d += __shfl_xor(d, 8);
      if (l15 == 0) dl[wc * TBM + wr * 32 + rt * 16 + quad * 4 + r] = d;
    }
  __syncthreads();
  if (tid < TBM) {
    float d = dl[0 * TBM + tid] + dl[1 * TBM + tid] + dl[2 * TBM + tid] +
              dl[3 * TBM + tid];
    denp[q * NN + r0 + tid] = d;
  }
}

// ---------------- K6: per-row edge dot + merge + correction + combine --------
__global__ __launch_bounds__(256) void k6_combine(
    const int* __restrict__ eidx, const float* __restrict__ bias,
    const int* __restrict__ cntArr, const int* __restrict__ slot,
    const short* __restrict__ qk, const float* __restrict__ mag,
    const float* __restrict__ phase, const float* __restrict__ nump,
    const float* __restrict__ denp, float* __restrict__ out, int nsplit) {
  __shared__ short qs[DQK];
  __shared__ int js[CAP];
  __shared__ float bs[CAP];
  __shared__ float ess[CAP];
  __shared__ int keepf[CAP];
  __shared__ f32x4 ncl[4][64];
  __shared__ float dcl[4];
  int i = blockIdx.x;
  int tid = threadIdx.x;
  int wave = tid >> 6;
  int lane = tid & 63;
  int cnt = cntArr[i];
  if (cnt > CAP) cnt = CAP;
  if (tid < 64)
    *reinterpret_cast<s16x4*>(&qs[tid * 4]) =
        *reinterpret_cast<const s16x4*>(qk + (size_t)i * DQK + tid * 4);
  for (int p = tid; p < cnt; p += 256) {
    int e = slot[i * CAP + p];
    js[p] = eidx[EE + e];
    bs[p] = bias[e];
  }
  __syncthreads();
  int sub = lane & 7;
  for (int p = wave * 8 + (lane >> 3); p < cnt; p += 32) {
    int j = js[p];
    const bf16x8* kb = reinterpret_cast<const bf16x8*>(qk + (size_t)j * DQK + sub * 32);
    const bf16x8* qa = reinterpret_cast<const bf16x8*>(qs + sub * 32);
    float sp = 0.f;
#pragma unroll
    for (int t = 0; t < 4; ++t) {
      bf16x8 qv = qa[t];
      bf16x8 kv = kb[t];
#pragma unroll
      for (int u = 0; u < 8; ++u) sp += b2f(qv[u]) * b2f(kv[u]);
    }
    sp += __shfl_xor(sp, 1);
    sp += __shfl_xor(sp, 2);
    sp += __shfl_xor(sp, 4);
    if (sub == 0) ess[p] = __expf(sp * SCALE);
  }
  __syncthreads();
  {
    float bsum = 0.f;
    int keep = 0;
    if (tid < cnt) {
      int j = js[tid];
      bsum = bs[tid];
      keep = 1;
      for (int qq = 0; qq < cnt; ++qq) {
        if (qq == tid || js[qq] != j) continue;
        if (qq < tid) { keep = 0; break; }
        bsum += bs[qq];
      }
    }
    __syncthreads();
    if (tid < cnt) { bs[tid] = bsum; keepf[tid] = keep; }
    __syncthreads();
  }
  const float* vbase = (lane < 32) ? (mag + 4 * lane) : (phase + 4 * lane - 128);
  f32x4 nc = {0.f, 0.f, 0.f, 0.f};
  float denc = 0.f;
  if (wave < nsplit) {
    nc = *reinterpret_cast<const f32x4*>(nump + ((size_t)wave * NN + i) * DQK + 4 * lane);
    if (lane == 0) denc = denp[wave * NN + i];
  }
  for (int p = wave; p < cnt; p += 4) {
    if (!keepf[p]) continue;
    float delta = ess[p] * expm1f(bs[p]);
    denc += delta;
    f32x4 v = *reinterpret_cast<const f32x4*>(vbase + (size_t)js[p] * DD);
    nc += delta * v;
  }
  ncl[wave][lane] = nc;
  if (lane == 0) dcl[wave] = denc;
  __syncthreads();
  if (wave == 0) {
    f32x4 nd = ncl[0][lane] + ncl[1][lane] + ncl[2][lane] + ncl[3][lane];
    float den = dcl[0] + dcl[1] + dcl[2] + dcl[3];
    f32x4 res = nd * (1.0f / den);
    if (lane < 32)
      *reinterpret_cast<f32x4*>(out + (size_t)i * DD + 4 * lane) = res;
    else
      *reinterpret_cast<f32x4*>(out + (size_t)NN * DD + (size_t)i * DD + 4 * lane - 128) = res;
  }
}

// ---------------- workspace layout -------------------------------------------
constexpr size_t OFF_QK = 0;                                  // 4 MiB bf16
constexpr size_t OFF_VT = (size_t)NN * DQK * 2;               // 4 MiB bf16
constexpr size_t OFF_BIAS = OFF_VT + (size_t)DQK * NN * 2;    // 1 MiB f32
constexpr size_t OFF_CNT = OFF_BIAS + (size_t)EE * 4;
constexpr size_t OFF_SLOT = OFF_CNT + (size_t)NN * 4;
constexpr size_t OFF_NUMP = (OFF_SLOT + (size_t)NN * CAP * 4 + 255) & ~(size_t)255;
constexpr size_t WS_NEED4 = OFF_NUMP + 4ull * NN * DQK * 4 + 4ull * NN * 4;
constexpr size_t WS_NEED2 = OFF_NUMP + 2ull * NN * DQK * 4 + 2ull * NN * 4;

extern "C" void kernel_launch(void* const* d_in, const int* in_sizes, int n_in,
                              void* d_out, int out_size, void* d_ws, size_t ws_size,
                              hipStream_t stream) {
  const float* mag = (const float*)d_in[0];
  const float* phase = (const float*)d_in[1];
  const int* eidx = (const int*)d_in[2];
  const float* rbf = (const float*)d_in[3];
  const float* W1 = (const float*)d_in[4];
  const float* b1 = (const float*)d_in[5];
  const float* W2 = (const float*)d_in[6];
  const float* b2 = (const float*)d_in[7];
  float* out = (float*)d_out;
  char* ws = (char*)d_ws;
  if (ws_size < WS_NEED2) return;
  int nsplit = (ws_size >= WS_NEED4) ? 4 : 2;

  short* qkb = (short*)(ws + OFF_QK);
  short* vtb = (short*)(ws + OFF_VT);
  float* bias = (float*)(ws + OFF_BIAS);
  int* cnt = (int*)(ws + OFF_CNT);
  int* slot = (int*)(ws + OFF_SLOT);
  float* nump = (float*)(ws + OFF_NUMP);
  float* denp = (float*)(ws + OFF_NUMP + (size_t)nsplit * NN * DQK * 4);

  hipMemsetAsync(cnt, 0, (size_t)NN * 4, stream);
  k1_mega<<<5120, 256, 0, stream>>>(mag, phase, qkb, vtb, rbf, W1, b1, W2, b2,
                                    eidx, bias, cnt, slot);
  if (nsplit == 4)
    k5_flash<4><<<(NN / TBM) * 4, 512, 0, stream>>>(qkb, vtb, nump, denp);
  else
    k5_flash<2><<<(NN / TBM) * 2, 512, 0, stream>>>(qkb, vtb, nump, denp);
  k6_combine<<<NN, 256, 0, stream>>>(eidx, bias, cnt, slot, qkb, mag, phase, nump,
                                     denp, out, nsplit);
}

// Round 12
// 270.494 us; speedup vs baseline: 1.1294x; 1.1294x over previous
//
#include <hip/hip_runtime.h>
#include <hip/hip_bf16.h>

#define NN 8192
#define DD 128
#define DQK 256
#define EE 262144
#define EDGE_DIM 50
#define HID 32
#define CAP 96                               // per-row edge cap (Poisson(32))
#define SCALE 0.08838834764831845f          // 1/sqrt(128)
#define SCALE_LOG2E 0.12752455522410585f    // SCALE * log2(e)

using f32x4 = __attribute__((ext_vector_type(4))) float;
using f32x2 = __attribute__((ext_vector_type(2))) float;
using bf16x8 = __attribute__((ext_vector_type(8))) short;  // 8 bf16 = 4 VGPRs
using s16x4 = __attribute__((ext_vector_type(4))) short;

static __device__ __forceinline__ short f2b(float f) {
  __hip_bfloat16 h = __float2bfloat16(f);
  return __builtin_bit_cast(short, h);
}
static __device__ __forceinline__ float b2f(short s) {
  unsigned u = ((unsigned)(unsigned short)s) << 16;
  return __builtin_bit_cast(float, u);
}
// async global->LDS, 16B per lane; lds dest = wave-uniform base + lane*16
static __device__ __forceinline__ void gll(const short* g, short* l) {
  __builtin_amdgcn_global_load_lds(
      (const __attribute__((address_space(1))) void*)g,
      (__attribute__((address_space(3))) void*)l, 16, 0, 0);
}

// ---------------- K1: heterogeneous prep + MLP, one dispatch -----------------
// blocks [0,4096):    qkb[n][0:128]=mag*cos, [128:256]=mag*sin; vb16=[mag|ph]
// blocks [4096,4608): vtb[f][n] transpose via 64x64 LDS tiles
// blocks [4608,5632): edge MLP bias + bucket scatter (R8-proven 1 edge/thread)
__global__ __launch_bounds__(256) void k1_mega(
    const float* __restrict__ mag, const float* __restrict__ phase,
    short* __restrict__ qkb, short* __restrict__ vtb, short* __restrict__ vb16,
    const float* __restrict__ rbf, const float* __restrict__ W1,
    const float* __restrict__ b1, const float* __restrict__ W2,
    const float* __restrict__ b2, const int* __restrict__ eidx,
    float* __restrict__ bias, int* __restrict__ cnt, int* __restrict__ slot) {
  __shared__ float tile[64][65];
  __shared__ alignas(16) float w1s[EDGE_DIM * HID];
  __shared__ alignas(16) float b1s[HID];
  __shared__ alignas(16) float w2s[HID];
  __shared__ float b2s;
  int b = blockIdx.x;
  int tid = threadIdx.x;
  if (b < 4096) {
    int t = b * 256 + tid;
    int n = t >> 7, d = t & 127;
    float m = mag[t], p = phase[t];
    float sn, cs;
    __sincosf(p, &sn, &cs);
    qkb[(size_t)n * DQK + d] = f2b(m * cs);
    qkb[(size_t)n * DQK + 128 + d] = f2b(m * sn);
    vb16[(size_t)n * DQK + d] = f2b(m);
    vb16[(size_t)n * DQK + 128 + d] = f2b(p);
    return;
  }
  if (b < 4608) {
    int r = b - 4096;
    int bn = r & 127, bd = (r >> 7) & 1, sel = r >> 8;
    const float* src = sel ? phase : mag;
#pragma unroll
    for (int rep = 0; rep < 16; ++rep) {
      int idx = rep * 256 + tid;
      int rr = idx >> 6, c = idx & 63;
      tile[rr][c] = src[(size_t)(bn * 64 + rr) * DD + bd * 64 + c];
    }
    __syncthreads();
#pragma unroll
    for (int rep = 0; rep < 16; ++rep) {
      int idx = rep * 256 + tid;
      int rr = idx >> 6, c = idx & 63;
      vtb[(size_t)(sel * 128 + bd * 64 + rr) * NN + bn * 64 + c] = f2b(tile[c][rr]);
    }
    return;
  }
  // ---- MLP branch (1 edge/thread) ----
  for (int k = tid; k < EDGE_DIM * HID; k += 256) w1s[k] = W1[k];
  if (tid < HID) { b1s[tid] = b1[tid]; w2s[tid] = W2[tid]; }
  if (tid == 0) b2s = b2[0];
  __syncthreads();
  int e = (b - 4608) * 256 + tid;
  const float* rrow = rbf + (size_t)e * EDGE_DIM;
  f32x4 r4[12];
#pragma unroll
  for (int k = 0; k < 12; ++k) r4[k] = *reinterpret_cast<const f32x4*>(rrow + 4 * k);
  f32x2 rt2 = *reinterpret_cast<const f32x2*>(rrow + 48);
  f32x4 h[8];
#pragma unroll
  for (int jj = 0; jj < 8; ++jj) h[jj] = reinterpret_cast<const f32x4*>(b1s)[jj];
#pragma unroll
  for (int k = 0; k < 12; ++k) {
#pragma unroll
    for (int qq = 0; qq < 4; ++qq) {
      const f32x4* wrow = reinterpret_cast<const f32x4*>(w1s + (4 * k + qq) * HID);
#pragma unroll
      for (int jj = 0; jj < 8; ++jj) h[jj] += r4[k][qq] * wrow[jj];
    }
  }
  {
    const f32x4* w48 = reinterpret_cast<const f32x4*>(w1s + 48 * HID);
    const f32x4* w49 = reinterpret_cast<const f32x4*>(w1s + 49 * HID);
#pragma unroll
    for (int jj = 0; jj < 8; ++jj) h[jj] += rt2.x * w48[jj] + rt2.y * w49[jj];
  }
  float outv = b2s;
#pragma unroll
  for (int jj = 0; jj < 8; ++jj) {
    f32x4 x = h[jj];
    f32x4 sl;
#pragma unroll
    for (int q = 0; q < 4; ++q) sl[q] = x[q] / (1.0f + __expf(-x[q]));
    f32x4 pr = sl * reinterpret_cast<const f32x4*>(w2s)[jj];
    outv += pr.x + pr.y + pr.z + pr.w;
  }
  bias[e] = outv;
  int i = eidx[e];
  int p = atomicAdd(&cnt[i], 1);
  if (p < CAP) slot[i * CAP + p] = e;
}

// ---------------- K5: fused dense flash (R8-proven structure) ----------------
// TBM=64 rows/block, 512 threads = 8 waves (2 row x 4 col). LDS exactly 80 KiB
// (Qs 32K + KV 32K + Ps 16K, dl overlaid on KV) -> 2 blocks/CU. Fine-grained
// K-slice double-buffering (4 x 16KB) is LOAD-BEARING for L2 reuse: fat-phase
// burst staging (R9) collapsed L2 hit rate (FETCH 14->278 MB). Do not coarsen.
// R11's early-V prefetch regressed (barrier drains vmcnt anyway) - reverted.
constexpr int TBM = 64;
constexpr int TBN = 128;

template <int NSPLIT>
__global__ __launch_bounds__(512, 4) void k5_flash(
    const short* __restrict__ qk,  // [N][256] bf16
    const short* __restrict__ vt,  // [256][N] bf16
    float* __restrict__ nump,      // [NSPLIT][N][256]
    float* __restrict__ denp) {    // [NSPLIT][N]
  constexpr int QCOLS = NN / NSPLIT;
  constexpr int NCHUNK = QCOLS / TBN;
  constexpr int GPQ = 8 / NSPLIT;
  __shared__ alignas(16) short Qs[TBM * 256];     // 32 KiB, swizzled
  __shared__ alignas(16) short KV[2 * TBN * 64];  // 32 KiB: K dbuf / V subtile
  __shared__ alignas(16) short Ps[TBM * 128];     // 16 KiB, swizzled
  int b = blockIdx.x;
  int q = (b & 7) / GPQ;
  int rb = (b >> 3) * GPQ + (b & (GPQ - 1));
  int tid = threadIdx.x;
  int w = tid >> 6, lane = tid & 63;
  int wr = w >> 2, wc = w & 3;
  int l15 = lane & 15, quad = lane >> 4;
  int rsw = l15 & 7;  // read-side swizzle key (row&7 == l15&7 for all frags)
  int wbase = w * 64; // lane-linear staging base per wave
  int r0 = rb * TBM;
  int cbase = q * QCOLS;

  // ---- stage Q tile once: 4 passes x 8KB, direct to LDS ----
#pragma unroll
  for (int p = 0; p < 4; ++p) {
    int idx = p * 512 + tid;
    int row = idx >> 5, gs = idx & 31;
    gll(qk + (size_t)(r0 + row) * DQK + ((gs ^ (row & 7)) * 8),
        &Qs[(p * 512 + wbase) * 8]);
  }

  f32x4 o[2][4] = {};
  float den[2][4] = {};
  __syncthreads();

  for (int ch = 0; ch < NCHUNK; ++ch) {
    int c0 = cbase + ch * TBN;
    // ---- stage K slice bk=0 into buf0 ----
#pragma unroll
    for (int p = 0; p < 2; ++p) {
      int idx = p * 512 + tid;
      int col = idx >> 3, gs = idx & 7;
      gll(qk + (size_t)(c0 + col) * DQK + ((gs ^ (col & 7)) * 8),
          &KV[(p * 512 + wbase) * 8]);
    }
    __syncthreads();
    f32x4 s[2][2] = {};
#pragma unroll
    for (int bk = 0; bk < 4; ++bk) {
      int buf = bk & 1;
      if (bk < 3) {
        int nb = buf ^ 1;
#pragma unroll
        for (int p = 0; p < 2; ++p) {
          int idx = p * 512 + tid;
          int col = idx >> 3, gs = idx & 7;
          gll(qk + (size_t)(c0 + col) * DQK + (bk + 1) * 64 + ((gs ^ (col & 7)) * 8),
              &KV[nb * 8192 + (p * 512 + wbase) * 8]);
        }
      }
#pragma unroll
      for (int ks = 0; ks < 2; ++ks) {
        int g = ks * 4 + quad;
        bf16x8 a[2], bb[2];
#pragma unroll
        for (int rt = 0; rt < 2; ++rt)
          a[rt] = *(const bf16x8*)&Qs[(wr * 32 + rt * 16 + l15) * 256 +
                                      ((bk * 8 + g) ^ rsw) * 8];
#pragma unroll
        for (int ct = 0; ct < 2; ++ct)
          bb[ct] = *(const bf16x8*)&KV[buf * 8192 + (wc * 32 + ct * 16 + l15) * 64 +
                                       (g ^ rsw) * 8];
#pragma unroll
        for (int rt = 0; rt < 2; ++rt)
#pragma unroll
          for (int ct = 0; ct < 2; ++ct)
            s[rt][ct] = __builtin_amdgcn_mfma_f32_16x16x32_bf16(a[rt], bb[ct],
                                                                s[rt][ct], 0, 0, 0);
      }
      __syncthreads();
    }
    // ---- exp + P->LDS (C layout, swizzled groups) + den ----
#pragma unroll
    for (int rt = 0; rt < 2; ++rt)
#pragma unroll
      for (int ct = 0; ct < 2; ++ct) {
        int col = wc * 32 + ct * 16 + l15;
        int cg = col >> 3, co = col & 7;
#pragma unroll
        for (int r = 0; r < 4; ++r) {
          float pv = exp2f(s[rt][ct][r] * SCALE_LOG2E);
          den[rt][r] += pv;
          int row = wr * 32 + rt * 16 + quad * 4 + r;
          Ps[row * 128 + ((cg ^ (row & 7)) * 8 + co)] = f2b(pv);
        }
      }
    __syncthreads();
    // ---- PV: V subtiles of 64 cols, staged direct to LDS ----
#pragma unroll
    for (int jb = 0; jb < 2; ++jb) {
#pragma unroll
      for (int p = 0; p < 4; ++p) {
        int idx = p * 512 + tid;
        int feat = idx >> 3, gs = idx & 7;
        gll(vt + (size_t)feat * NN + c0 + jb * 64 + ((gs ^ (feat & 7)) * 8),
            &KV[(p * 512 + wbase) * 8]);
      }
      __syncthreads();
#pragma unroll
      for (int ks = 0; ks < 2; ++ks) {
        int g = ks * 4 + quad;
        bf16x8 pa[2], vb[4];
#pragma unroll
        for (int rt = 0; rt < 2; ++rt) {
          int row = wr * 32 + rt * 16 + l15;
          pa[rt] = *(const bf16x8*)&Ps[row * 128 +
                                       (((jb * 8 + g) ^ (row & 7)) * 8)];
        }
#pragma unroll
        for (int ft = 0; ft < 4; ++ft)
          vb[ft] = *(const bf16x8*)&KV[(wc * 64 + ft * 16 + l15) * 64 + (g ^ rsw) * 8];
#pragma unroll
        for (int rt = 0; rt < 2; ++rt)
#pragma unroll
          for (int ft = 0; ft < 4; ++ft)
            o[rt][ft] = __builtin_amdgcn_mfma_f32_16x16x32_bf16(pa[rt], vb[ft],
                                                                o[rt][ft], 0, 0, 0);
      }
      __syncthreads();
    }
  }
  // ---- epilogue: write partial num ----
  float* npB = nump + (size_t)q * NN * DQK;
#pragma unroll
  for (int rt = 0; rt < 2; ++rt)
#pragma unroll
    for (int ft = 0; ft < 4; ++ft) {
      int row = r0 + wr * 32 + rt * 16 + quad * 4;
      int feat = wc * 64 + ft * 16 + l15;
#pragma unroll
      for (int r = 0; r < 4; ++r)
        npB[(size_t)(row + r) * DQK + feat] = o[rt][ft][r];
    }
  // ---- den: reduce l15 within quad, then across col-waves (dl overlays KV) --
  float* dl = reinterpret_cast<float*>(KV);  // [4][TBM], KV dead at epilogue
#pragma unroll
  for (int rt = 0; rt < 2; ++rt)
#pragma unroll
    for (int r = 0; r < 4; ++r) {
      float d = den[rt][r];
      d += __shfl_xor(d, 1);
      d += __shfl_xor(d, 2);
      d += __shfl_xor(d, 4);
      d += __shfl_xor(d, 8);
      if (l15 == 0) dl[wc * TBM + wr * 32 + rt * 16 + quad * 4 + r] = d;
    }
  __syncthreads();
  if (tid < TBM) {
    float d = dl[0 * TBM + tid] + dl[1 * TBM + tid] + dl[2 * TBM + tid] +
              dl[3 * TBM + tid];
    denp[q * NN + r0 + tid] = d;
  }
}

// ---------------- K6: one wave per row -- dot + merge + correction + combine -
// 64 threads: all barriers are single-wave (near-free). V-gather uses bf16
// vb16 rows (512B/edge, halves bytes vs f32); two 32-lane groups process two
// edges concurrently (halves the serial latency chain).
__global__ __launch_bounds__(64) void k6_combine(
    const int* __restrict__ eidx, const float* __restrict__ bias,
    const int* __restrict__ cntArr, const int* __restrict__ slot,
    const short* __restrict__ qk, const short* __restrict__ vb16,
    const float* __restrict__ nump, const float* __restrict__ denp,
    float* __restrict__ out, int nsplit) {
  __shared__ short qs[DQK];
  __shared__ int js[CAP];
  __shared__ float bs[CAP];
  __shared__ float ess[CAP];
  __shared__ int keepf[CAP];
  __shared__ float ncl[2][32][8];
  __shared__ float dcl[2];
  int i = blockIdx.x;
  int lane = threadIdx.x;
  int cnt = cntArr[i];
  if (cnt > CAP) cnt = CAP;
  *reinterpret_cast<s16x4*>(&qs[lane * 4]) =
      *reinterpret_cast<const s16x4*>(qk + (size_t)i * DQK + lane * 4);
  for (int p = lane; p < cnt; p += 64) {
    int e = slot[i * CAP + p];
    js[p] = eidx[EE + e];
    bs[p] = bias[e];
  }
  __syncthreads();
  // ---- per-edge exp(score): 8 lanes per edge, 8 edges in flight ----
  int sub = lane & 7;
  for (int p = lane >> 3; p < cnt; p += 8) {
    int j = js[p];
    const bf16x8* kb = reinterpret_cast<const bf16x8*>(qk + (size_t)j * DQK + sub * 32);
    const bf16x8* qa = reinterpret_cast<const bf16x8*>(qs + sub * 32);
    float sp = 0.f;
#pragma unroll
    for (int t = 0; t < 4; ++t) {
      bf16x8 qv = qa[t];
      bf16x8 kv = kb[t];
#pragma unroll
      for (int u = 0; u < 8; ++u) sp += b2f(qv[u]) * b2f(kv[u]);
    }
    sp += __shfl_xor(sp, 1);
    sp += __shfl_xor(sp, 2);
    sp += __shfl_xor(sp, 4);
    if (sub == 0) ess[p] = __expf(sp * SCALE);
  }
  __syncthreads();
  // ---- exact duplicate-(i,j) merge: first occurrence keeps summed beta ----
  {
    int myp[2];
    float mybsum[2];
    int mykeep[2];
    int nm = 0;
    for (int p = lane; p < cnt; p += 64) {
      int j = js[p];
      float bsum = bs[p];
      int keep = 1;
      for (int qq = 0; qq < cnt; ++qq) {
        if (qq == p || js[qq] != j) continue;
        if (qq < p) { keep = 0; break; }
        bsum += bs[qq];
      }
      myp[nm] = p; mybsum[nm] = bsum; mykeep[nm] = keep; ++nm;
    }
    __syncthreads();
    for (int k = 0; k < nm; ++k) { bs[myp[k]] = mybsum[k]; keepf[myp[k]] = mykeep[k]; }
    __syncthreads();
  }
  // ---- correction: 2 groups of 32 lanes, one edge each; bf16x8 V-gather ----
  int grp = lane >> 5;
  int l31 = lane & 31;  // feats l31*8 .. l31*8+7
  f32x4 nc0 = {0.f, 0.f, 0.f, 0.f}, nc1 = {0.f, 0.f, 0.f, 0.f};
  float denc = 0.f;
  for (int p = grp; p < cnt; p += 2) {
    if (!keepf[p]) continue;
    float delta = ess[p] * expm1f(bs[p]);
    denc += delta;
    bf16x8 v = *reinterpret_cast<const bf16x8*>(vb16 + (size_t)js[p] * DQK + l31 * 8);
#pragma unroll
    for (int u = 0; u < 4; ++u) nc0[u] += delta * b2f(v[u]);
#pragma unroll
    for (int u = 0; u < 4; ++u) nc1[u] += delta * b2f(v[4 + u]);
  }
#pragma unroll
  for (int u = 0; u < 4; ++u) {
    ncl[grp][l31][u] = nc0[u];
    ncl[grp][l31][4 + u] = nc1[u];
  }
  if (l31 == 0) dcl[grp] = denc;
  __syncthreads();
  if (grp == 0) {
    float den = dcl[0] + dcl[1];
    f32x4 a0, a1;
#pragma unroll
    for (int u = 0; u < 4; ++u) {
      a0[u] = ncl[0][l31][u] + ncl[1][l31][u];
      a1[u] = ncl[0][l31][4 + u] + ncl[1][l31][4 + u];
    }
    for (int qq = 0; qq < nsplit; ++qq) {
      const float* np = nump + ((size_t)qq * NN + i) * DQK + l31 * 8;
      a0 += *reinterpret_cast<const f32x4*>(np);
      a1 += *reinterpret_cast<const f32x4*>(np + 4);
      den += denp[qq * NN + i];
    }
    float inv = 1.0f / den;
    a0 *= inv;
    a1 *= inv;
    // feats f = l31*8..+7; f<128 -> new_mag, else new_phase (no 128-crossing)
    float* dst = (l31 < 16) ? (out + (size_t)i * DD + l31 * 8)
                            : (out + (size_t)NN * DD + (size_t)i * DD + l31 * 8 - 128);
    *reinterpret_cast<f32x4*>(dst) = a0;
    *reinterpret_cast<f32x4*>(dst + 4) = a1;
  }
}

// ---------------- workspace layout -------------------------------------------
constexpr size_t OFF_QK = 0;                                   // 4 MiB bf16
constexpr size_t OFF_VT = (size_t)NN * DQK * 2;                // 4 MiB bf16
constexpr size_t OFF_VB16 = OFF_VT + (size_t)DQK * NN * 2;     // 4 MiB bf16
constexpr size_t OFF_BIAS = OFF_VB16 + (size_t)NN * DQK * 2;   // 1 MiB f32
constexpr size_t OFF_CNT = OFF_BIAS + (size_t)EE * 4;
constexpr size_t OFF_SLOT = OFF_CNT + (size_t)NN * 4;
constexpr size_t OFF_NUMP = (OFF_SLOT + (size_t)NN * CAP * 4 + 255) & ~(size_t)255;
constexpr size_t WS_NEED4 = OFF_NUMP + 4ull * NN * DQK * 4 + 4ull * NN * 4;
constexpr size_t WS_NEED2 = OFF_NUMP + 2ull * NN * DQK * 4 + 2ull * NN * 4;

extern "C" void kernel_launch(void* const* d_in, const int* in_sizes, int n_in,
                              void* d_out, int out_size, void* d_ws, size_t ws_size,
                              hipStream_t stream) {
  const float* mag = (const float*)d_in[0];
  const float* phase = (const float*)d_in[1];
  const int* eidx = (const int*)d_in[2];
  const float* rbf = (const float*)d_in[3];
  const float* W1 = (const float*)d_in[4];
  const float* b1 = (const float*)d_in[5];
  const float* W2 = (const float*)d_in[6];
  const float* b2 = (const float*)d_in[7];
  float* out = (float*)d_out;
  char* ws = (char*)d_ws;
  if (ws_size < WS_NEED2) return;
  int nsplit = (ws_size >= WS_NEED4) ? 4 : 2;

  short* qkb = (short*)(ws + OFF_QK);
  short* vtb = (short*)(ws + OFF_VT);
  short* vb16 = (short*)(ws + OFF_VB16);
  float* bias = (float*)(ws + OFF_BIAS);
  int* cnt = (int*)(ws + OFF_CNT);
  int* slot = (int*)(ws + OFF_SLOT);
  float* nump = (float*)(ws + OFF_NUMP);
  float* denp = (float*)(ws + OFF_NUMP + (size_t)nsplit * NN * DQK * 4);

  hipMemsetAsync(cnt, 0, (size_t)NN * 4, stream);
  k1_mega<<<5632, 256, 0, stream>>>(mag, phase, qkb, vtb, vb16, rbf, W1, b1, W2,
                                    b2, eidx, bias, cnt, slot);
  if (nsplit == 4)
    k5_flash<4><<<(NN / TBM) * 4, 512, 0, stream>>>(qkb, vtb, nump, denp);
  else
    k5_flash<2><<<(NN / TBM) * 2, 512, 0, stream>>>(qkb, vtb, nump, denp);
  k6_combine<<<NN, 64, 0, stream>>>(eidx, bias, cnt, slot, qkb, vb16, nump, denp,
                                    out, nsplit);
}

// Round 13
// 267.915 us; speedup vs baseline: 1.1403x; 1.0096x over previous
//
#include <hip/hip_runtime.h>
#include <hip/hip_bf16.h>

#define NN 8192
#define DD 128
#define DQK 256
#define EE 262144
#define EDGE_DIM 50
#define HID 32
#define CAP 96                               // per-row edge cap (Poisson(32))
#define SCALE 0.08838834764831845f          // 1/sqrt(128)
#define SCALE_LOG2E 0.12752455522410585f    // SCALE * log2(e)

using f32x4 = __attribute__((ext_vector_type(4))) float;
using f32x2 = __attribute__((ext_vector_type(2))) float;
using bf16x8 = __attribute__((ext_vector_type(8))) short;  // 8 bf16 = 4 VGPRs
using s16x4 = __attribute__((ext_vector_type(4))) short;

static __device__ __forceinline__ short f2b(float f) {
  __hip_bfloat16 h = __float2bfloat16(f);
  return __builtin_bit_cast(short, h);
}
static __device__ __forceinline__ float b2f(short s) {
  unsigned u = ((unsigned)(unsigned short)s) << 16;
  return __builtin_bit_cast(float, u);
}
// async global->LDS, 16B per lane; lds dest = wave-uniform base + lane*16
static __device__ __forceinline__ void gll(const short* g, short* l) {
  __builtin_amdgcn_global_load_lds(
      (const __attribute__((address_space(1))) void*)g,
      (__attribute__((address_space(3))) void*)l, 16, 0, 0);
}

// ---------------- K1: heterogeneous prep + MLP, one dispatch -----------------
// blocks [0,4096):    qkb[n][0:128]=mag*cos, [128:256]=mag*sin; vb16=[mag|ph]
// blocks [4096,4608): vtb[f][n] transpose via 64x64 LDS tiles
// blocks [4608,5632): edge MLP. W1/b1/W2/b2 read with wave-uniform indices ->
//   s_load + SGPR broadcast (scalar cache), NO LDS pipe in the hot loop.
//   (R12 profile model: 400 uniform ds_read_b128/edge-wave = ~30us of LDS
//   serialization; scalar path removes it.)
__global__ __launch_bounds__(256) void k1_mega(
    const float* __restrict__ mag, const float* __restrict__ phase,
    short* __restrict__ qkb, short* __restrict__ vtb, short* __restrict__ vb16,
    const float* __restrict__ rbf, const float* __restrict__ W1,
    const float* __restrict__ b1, const float* __restrict__ W2,
    const float* __restrict__ b2, const int* __restrict__ eidx,
    float* __restrict__ bias, int* __restrict__ cnt, int* __restrict__ slot) {
  __shared__ float tile[64][65];
  int b = blockIdx.x;
  int tid = threadIdx.x;
  if (b < 4096) {
    int t = b * 256 + tid;
    int n = t >> 7, d = t & 127;
    float m = mag[t], p = phase[t];
    float sn, cs;
    __sincosf(p, &sn, &cs);
    qkb[(size_t)n * DQK + d] = f2b(m * cs);
    qkb[(size_t)n * DQK + 128 + d] = f2b(m * sn);
    vb16[(size_t)n * DQK + d] = f2b(m);
    vb16[(size_t)n * DQK + 128 + d] = f2b(p);
    return;
  }
  if (b < 4608) {
    int r = b - 4096;
    int bn = r & 127, bd = (r >> 7) & 1, sel = r >> 8;
    const float* src = sel ? phase : mag;
#pragma unroll
    for (int rep = 0; rep < 16; ++rep) {
      int idx = rep * 256 + tid;
      int rr = idx >> 6, c = idx & 63;
      tile[rr][c] = src[(size_t)(bn * 64 + rr) * DD + bd * 64 + c];
    }
    __syncthreads();
#pragma unroll
    for (int rep = 0; rep < 16; ++rep) {
      int idx = rep * 256 + tid;
      int rr = idx >> 6, c = idx & 63;
      vtb[(size_t)(sel * 128 + bd * 64 + rr) * NN + bn * 64 + c] = f2b(tile[c][rr]);
    }
    return;
  }
  // ---- MLP branch (1 edge/thread, scalar-broadcast weights) ----
  int e = (b - 4608) * 256 + tid;
  const float* rrow = rbf + (size_t)e * EDGE_DIM;
  f32x4 r4[12];
#pragma unroll
  for (int k = 0; k < 12; ++k) r4[k] = *reinterpret_cast<const f32x4*>(rrow + 4 * k);
  f32x2 rt2 = *reinterpret_cast<const f32x2*>(rrow + 48);
  float h[HID];
#pragma unroll
  for (int jj = 0; jj < HID; ++jj) h[jj] = b1[jj];  // uniform -> s_load
#pragma unroll
  for (int k = 0; k < 48; ++k) {
    float r = r4[k >> 2][k & 3];
#pragma unroll
    for (int jj = 0; jj < HID; ++jj) h[jj] += r * W1[k * HID + jj];  // s_load
  }
#pragma unroll
  for (int jj = 0; jj < HID; ++jj)
    h[jj] += rt2.x * W1[48 * HID + jj] + rt2.y * W1[49 * HID + jj];
  float outv = b2[0];
#pragma unroll
  for (int jj = 0; jj < HID; ++jj) {
    float x = h[jj];
    outv += W2[jj] * (x / (1.0f + __expf(-x)));
  }
  bias[e] = outv;
  int i = eidx[e];
  int p = atomicAdd(&cnt[i], 1);
  if (p < CAP) slot[i * CAP + p] = e;
}

// ---------------- K5: fused dense flash (R8-proven structure) ----------------
// TBM=64 rows/block, 512 threads = 8 waves (2 row x 4 col). LDS exactly 80 KiB
// (Qs 32K + KV 32K + Ps 16K, dl overlaid on KV) -> 2 blocks/CU. Fine-grained
// K-slice double-buffering (4 x 16KB) is LOAD-BEARING for L2 reuse: fat-phase
// burst staging (R9) collapsed L2 hit rate (FETCH 14->278 MB). Do not coarsen.
// R11's early-V prefetch regressed (barrier drains vmcnt anyway) - reverted.
constexpr int TBM = 64;
constexpr int TBN = 128;

template <int NSPLIT>
__global__ __launch_bounds__(512, 4) void k5_flash(
    const short* __restrict__ qk,  // [N][256] bf16
    const short* __restrict__ vt,  // [256][N] bf16
    float* __restrict__ nump,      // [NSPLIT][N][256]
    float* __restrict__ denp) {    // [NSPLIT][N]
  constexpr int QCOLS = NN / NSPLIT;
  constexpr int NCHUNK = QCOLS / TBN;
  constexpr int GPQ = 8 / NSPLIT;
  __shared__ alignas(16) short Qs[TBM * 256];     // 32 KiB, swizzled
  __shared__ alignas(16) short KV[2 * TBN * 64];  // 32 KiB: K dbuf / V subtile
  __shared__ alignas(16) short Ps[TBM * 128];     // 16 KiB, swizzled
  int b = blockIdx.x;
  int q = (b & 7) / GPQ;
  int rb = (b >> 3) * GPQ + (b & (GPQ - 1));
  int tid = threadIdx.x;
  int w = tid >> 6, lane = tid & 63;
  int wr = w >> 2, wc = w & 3;
  int l15 = lane & 15, quad = lane >> 4;
  int rsw = l15 & 7;  // read-side swizzle key (row&7 == l15&7 for all frags)
  int wbase = w * 64; // lane-linear staging base per wave
  int r0 = rb * TBM;
  int cbase = q * QCOLS;

  // ---- stage Q tile once: 4 passes x 8KB, direct to LDS ----
#pragma unroll
  for (int p = 0; p < 4; ++p) {
    int idx = p * 512 + tid;
    int row = idx >> 5, gs = idx & 31;
    gll(qk + (size_t)(r0 + row) * DQK + ((gs ^ (row & 7)) * 8),
        &Qs[(p * 512 + wbase) * 8]);
  }

  f32x4 o[2][4] = {};
  float den[2][4] = {};
  __syncthreads();

  for (int ch = 0; ch < NCHUNK; ++ch) {
    int c0 = cbase + ch * TBN;
    // ---- stage K slice bk=0 into buf0 ----
#pragma unroll
    for (int p = 0; p < 2; ++p) {
      int idx = p * 512 + tid;
      int col = idx >> 3, gs = idx & 7;
      gll(qk + (size_t)(c0 + col) * DQK + ((gs ^ (col & 7)) * 8),
          &KV[(p * 512 + wbase) * 8]);
    }
    __syncthreads();
    f32x4 s[2][2] = {};
#pragma unroll
    for (int bk = 0; bk < 4; ++bk) {
      int buf = bk & 1;
      if (bk < 3) {
        int nb = buf ^ 1;
#pragma unroll
        for (int p = 0; p < 2; ++p) {
          int idx = p * 512 + tid;
          int col = idx >> 3, gs = idx & 7;
          gll(qk + (size_t)(c0 + col) * DQK + (bk + 1) * 64 + ((gs ^ (col & 7)) * 8),
              &KV[nb * 8192 + (p * 512 + wbase) * 8]);
        }
      }
#pragma unroll
      for (int ks = 0; ks < 2; ++ks) {
        int g = ks * 4 + quad;
        bf16x8 a[2], bb[2];
#pragma unroll
        for (int rt = 0; rt < 2; ++rt)
          a[rt] = *(const bf16x8*)&Qs[(wr * 32 + rt * 16 + l15) * 256 +
                                      ((bk * 8 + g) ^ rsw) * 8];
#pragma unroll
        for (int ct = 0; ct < 2; ++ct)
          bb[ct] = *(const bf16x8*)&KV[buf * 8192 + (wc * 32 + ct * 16 + l15) * 64 +
                                       (g ^ rsw) * 8];
#pragma unroll
        for (int rt = 0; rt < 2; ++rt)
#pragma unroll
          for (int ct = 0; ct < 2; ++ct)
            s[rt][ct] = __builtin_amdgcn_mfma_f32_16x16x32_bf16(a[rt], bb[ct],
                                                                s[rt][ct], 0, 0, 0);
      }
      __syncthreads();
    }
    // ---- exp + P->LDS (C layout, swizzled groups) + den ----
#pragma unroll
    for (int rt = 0; rt < 2; ++rt)
#pragma unroll
      for (int ct = 0; ct < 2; ++ct) {
        int col = wc * 32 + ct * 16 + l15;
        int cg = col >> 3, co = col & 7;
#pragma unroll
        for (int r = 0; r < 4; ++r) {
          float pv = exp2f(s[rt][ct][r] * SCALE_LOG2E);
          den[rt][r] += pv;
          int row = wr * 32 + rt * 16 + quad * 4 + r;
          Ps[row * 128 + ((cg ^ (row & 7)) * 8 + co)] = f2b(pv);
        }
      }
    __syncthreads();
    // ---- PV: V subtiles of 64 cols, staged direct to LDS ----
#pragma unroll
    for (int jb = 0; jb < 2; ++jb) {
#pragma unroll
      for (int p = 0; p < 4; ++p) {
        int idx = p * 512 + tid;
        int feat = idx >> 3, gs = idx & 7;
        gll(vt + (size_t)feat * NN + c0 + jb * 64 + ((gs ^ (feat & 7)) * 8),
            &KV[(p * 512 + wbase) * 8]);
      }
      __syncthreads();
#pragma unroll
      for (int ks = 0; ks < 2; ++ks) {
        int g = ks * 4 + quad;
        bf16x8 pa[2], vb[4];
#pragma unroll
        for (int rt = 0; rt < 2; ++rt) {
          int row = wr * 32 + rt * 16 + l15;
          pa[rt] = *(const bf16x8*)&Ps[row * 128 +
                                       (((jb * 8 + g) ^ (row & 7)) * 8)];
        }
#pragma unroll
        for (int ft = 0; ft < 4; ++ft)
          vb[ft] = *(const bf16x8*)&KV[(wc * 64 + ft * 16 + l15) * 64 + (g ^ rsw) * 8];
#pragma unroll
        for (int rt = 0; rt < 2; ++rt)
#pragma unroll
          for (int ft = 0; ft < 4; ++ft)
            o[rt][ft] = __builtin_amdgcn_mfma_f32_16x16x32_bf16(pa[rt], vb[ft],
                                                                o[rt][ft], 0, 0, 0);
      }
      __syncthreads();
    }
  }
  // ---- epilogue: write partial num ----
  float* npB = nump + (size_t)q * NN * DQK;
#pragma unroll
  for (int rt = 0; rt < 2; ++rt)
#pragma unroll
    for (int ft = 0; ft < 4; ++ft) {
      int row = r0 + wr * 32 + rt * 16 + quad * 4;
      int feat = wc * 64 + ft * 16 + l15;
#pragma unroll
      for (int r = 0; r < 4; ++r)
        npB[(size_t)(row + r) * DQK + feat] = o[rt][ft][r];
    }
  // ---- den: reduce l15 within quad, then across col-waves (dl overlays KV) --
  float* dl = reinterpret_cast<float*>(KV);  // [4][TBM], KV dead at epilogue
#pragma unroll
  for (int rt = 0; rt < 2; ++rt)
#pragma unroll
    for (int r = 0; r < 4; ++r) {
      float d = den[rt][r];
      d += __shfl_xor(d, 1);
      d += __shfl_xor(d, 2);
      d += __shfl_xor(d, 4);
      d += __shfl_xor(d, 8);
      if (l15 == 0) dl[wc * TBM + wr * 32 + rt * 16 + quad * 4 + r] = d;
    }
  __syncthreads();
  if (tid < TBM) {
    float d = dl[0 * TBM + tid] + dl[1 * TBM + tid] + dl[2 * TBM + tid] +
              dl[3 * TBM + tid];
    denp[q * NN + r0 + tid] = d;
  }
}

// ---------------- K6: one wave per row -- dot + merge + correction + combine -
__global__ __launch_bounds__(64) void k6_combine(
    const int* __restrict__ eidx, const float* __restrict__ bias,
    const int* __restrict__ cntArr, const int* __restrict__ slot,
    const short* __restrict__ qk, const short* __restrict__ vb16,
    const float* __restrict__ nump, const float* __restrict__ denp,
    float* __restrict__ out, int nsplit) {
  __shared__ short qs[DQK];
  __shared__ int js[CAP];
  __shared__ float bs[CAP];
  __shared__ float ess[CAP];
  __shared__ int keepf[CAP];
  __shared__ float ncl[2][32][8];
  __shared__ float dcl[2];
  int i = blockIdx.x;
  int lane = threadIdx.x;
  int cnt = cntArr[i];
  if (cnt > CAP) cnt = CAP;
  *reinterpret_cast<s16x4*>(&qs[lane * 4]) =
      *reinterpret_cast<const s16x4*>(qk + (size_t)i * DQK + lane * 4);
  for (int p = lane; p < cnt; p += 64) {
    int e = slot[i * CAP + p];
    js[p] = eidx[EE + e];
    bs[p] = bias[e];
  }
  __syncthreads();
  // ---- per-edge exp(score): 8 lanes per edge, 8 edges in flight ----
  int sub = lane & 7;
  for (int p = lane >> 3; p < cnt; p += 8) {
    int j = js[p];
    const bf16x8* kb = reinterpret_cast<const bf16x8*>(qk + (size_t)j * DQK + sub * 32);
    const bf16x8* qa = reinterpret_cast<const bf16x8*>(qs + sub * 32);
    float sp = 0.f;
#pragma unroll
    for (int t = 0; t < 4; ++t) {
      bf16x8 qv = qa[t];
      bf16x8 kv = kb[t];
#pragma unroll
      for (int u = 0; u < 8; ++u) sp += b2f(qv[u]) * b2f(kv[u]);
    }
    sp += __shfl_xor(sp, 1);
    sp += __shfl_xor(sp, 2);
    sp += __shfl_xor(sp, 4);
    if (sub == 0) ess[p] = __expf(sp * SCALE);
  }
  __syncthreads();
  // ---- exact duplicate-(i,j) merge: first occurrence keeps summed beta ----
  {
    int myp[2];
    float mybsum[2];
    int mykeep[2];
    int nm = 0;
    for (int p = lane; p < cnt; p += 64) {
      int j = js[p];
      float bsum = bs[p];
      int keep = 1;
      for (int qq = 0; qq < cnt; ++qq) {
        if (qq == p || js[qq] != j) continue;
        if (qq < p) { keep = 0; break; }
        bsum += bs[qq];
      }
      myp[nm] = p; mybsum[nm] = bsum; mykeep[nm] = keep; ++nm;
    }
    __syncthreads();
    for (int k = 0; k < nm; ++k) { bs[myp[k]] = mybsum[k]; keepf[myp[k]] = mykeep[k]; }
    __syncthreads();
  }
  // ---- correction: 2 groups of 32 lanes, one edge each; bf16x8 V-gather ----
  int grp = lane >> 5;
  int l31 = lane & 31;  // feats l31*8 .. l31*8+7
  f32x4 nc0 = {0.f, 0.f, 0.f, 0.f}, nc1 = {0.f, 0.f, 0.f, 0.f};
  float denc = 0.f;
  for (int p = grp; p < cnt; p += 2) {
    if (!keepf[p]) continue;
    float delta = ess[p] * expm1f(bs[p]);
    denc += delta;
    bf16x8 v = *reinterpret_cast<const bf16x8*>(vb16 + (size_t)js[p] * DQK + l31 * 8);
#pragma unroll
    for (int u = 0; u < 4; ++u) nc0[u] += delta * b2f(v[u]);
#pragma unroll
    for (int u = 0; u < 4; ++u) nc1[u] += delta * b2f(v[4 + u]);
  }
#pragma unroll
  for (int u = 0; u < 4; ++u) {
    ncl[grp][l31][u] = nc0[u];
    ncl[grp][l31][4 + u] = nc1[u];
  }
  if (l31 == 0) dcl[grp] = denc;
  __syncthreads();
  if (grp == 0) {
    float den = dcl[0] + dcl[1];
    f32x4 a0, a1;
#pragma unroll
    for (int u = 0; u < 4; ++u) {
      a0[u] = ncl[0][l31][u] + ncl[1][l31][u];
      a1[u] = ncl[0][l31][4 + u] + ncl[1][l31][4 + u];
    }
    for (int qq = 0; qq < nsplit; ++qq) {
      const float* np = nump + ((size_t)qq * NN + i) * DQK + l31 * 8;
      a0 += *reinterpret_cast<const f32x4*>(np);
      a1 += *reinterpret_cast<const f32x4*>(np + 4);
      den += denp[qq * NN + i];
    }
    float inv = 1.0f / den;
    a0 *= inv;
    a1 *= inv;
    // feats f = l31*8..+7; f<128 -> new_mag, else new_phase (no 128-crossing)
    float* dst = (l31 < 16) ? (out + (size_t)i * DD + l31 * 8)
                            : (out + (size_t)NN * DD + (size_t)i * DD + l31 * 8 - 128);
    *reinterpret_cast<f32x4*>(dst) = a0;
    *reinterpret_cast<f32x4*>(dst + 4) = a1;
  }
}

// ---------------- workspace layout -------------------------------------------
constexpr size_t OFF_QK = 0;                                   // 4 MiB bf16
constexpr size_t OFF_VT = (size_t)NN * DQK * 2;                // 4 MiB bf16
constexpr size_t OFF_VB16 = OFF_VT + (size_t)DQK * NN * 2;     // 4 MiB bf16
constexpr size_t OFF_BIAS = OFF_VB16 + (size_t)NN * DQK * 2;   // 1 MiB f32
constexpr size_t OFF_CNT = OFF_BIAS + (size_t)EE * 4;
constexpr size_t OFF_SLOT = OFF_CNT + (size_t)NN * 4;
constexpr size_t OFF_NUMP = (OFF_SLOT + (size_t)NN * CAP * 4 + 255) & ~(size_t)255;
constexpr size_t WS_NEED4 = OFF_NUMP + 4ull * NN * DQK * 4 + 4ull * NN * 4;
constexpr size_t WS_NEED2 = OFF_NUMP + 2ull * NN * DQK * 4 + 2ull * NN * 4;

extern "C" void kernel_launch(void* const* d_in, const int* in_sizes, int n_in,
                              void* d_out, int out_size, void* d_ws, size_t ws_size,
                              hipStream_t stream) {
  const float* mag = (const float*)d_in[0];
  const float* phase = (const float*)d_in[1];
  const int* eidx = (const int*)d_in[2];
  const float* rbf = (const float*)d_in[3];
  const float* W1 = (const float*)d_in[4];
  const float* b1 = (const float*)d_in[5];
  const float* W2 = (const float*)d_in[6];
  const float* b2 = (const float*)d_in[7];
  float* out = (float*)d_out;
  char* ws = (char*)d_ws;
  if (ws_size < WS_NEED2) return;
  int nsplit = (ws_size >= WS_NEED4) ? 4 : 2;

  short* qkb = (short*)(ws + OFF_QK);
  short* vtb = (short*)(ws + OFF_VT);
  short* vb16 = (short*)(ws + OFF_VB16);
  float* bias = (float*)(ws + OFF_BIAS);
  int* cnt = (int*)(ws + OFF_CNT);
  int* slot = (int*)(ws + OFF_SLOT);
  float* nump = (float*)(ws + OFF_NUMP);
  float* denp = (float*)(ws + OFF_NUMP + (size_t)nsplit * NN * DQK * 4);

  hipMemsetAsync(cnt, 0, (size_t)NN * 4, stream);
  k1_mega<<<5632, 256, 0, stream>>>(mag, phase, qkb, vtb, vb16, rbf, W1, b1, W2,
                                    b2, eidx, bias, cnt, slot);
  if (nsplit == 4)
    k5_flash<4><<<(NN / TBM) * 4, 512, 0, stream>>>(qkb, vtb, nump, denp);
  else
    k5_flash<2><<<(NN / TBM) * 2, 512, 0, stream>>>(qkb, vtb, nump, denp);
  k6_combine<<<NN, 64, 0, stream>>>(eidx, bias, cnt, slot, qkb, vb16, nump, denp,
                                    out, nsplit);
}